// Round 16
// baseline (23.516 us; speedup 1.0000x reference)
//
#include <hip/hip_runtime.h>
#include <hip/hip_bf16.h>

#define LENGTH 4000
#define NPAD   4096
#define NB     8
#define CH     64
#define NP     4
#define NT2    32               // n-cols per k_mix block
#define BSTR   72               // k_mix LDS stride (ushorts)
#define HST    72               // Kronecker LDS stride (ushorts): 2-way max alias

using ushort8 = __attribute__((ext_vector_type(8))) unsigned short;
using ushort4v = __attribute__((ext_vector_type(4))) unsigned short;
using short8v = __attribute__((ext_vector_type(8))) short;
using f32x4   = __attribute__((ext_vector_type(4))) float;
using uint4v  = __attribute__((ext_vector_type(4))) unsigned int;

__device__ __forceinline__ unsigned short f2bu(float f) {
    __hip_bfloat16 h = __float2bfloat16(f);
    return __builtin_bit_cast(unsigned short, h);
}

// H64[i][j] = (-1)^popcount(i&j), bf16-exact. Fragment for 16x16x32 MFMA:
// lane (l15,lq) needs H[k0+e][j] (A-side) or H[k0+e][j] (B-side), e=0..7,
// k0 = ks*32+lq*8 (8-aligned). parity(k&j) = parity(k0&j) ^ parity(e & (j&7)).
// pat[] encodes the e-pattern (per-thread constant); flip applies parity(k0&j).
__device__ __forceinline__ short8v hfrag(const unsigned pat[4], int j, int k0) {
    const unsigned flip = (__popc(j & k0) & 1) ? 0x80008000u : 0u;
    uint4v r;
    r[0] = pat[0] ^ flip; r[1] = pat[1] ^ flip;
    r[2] = pat[2] ^ flip; r[3] = pat[3] ^ flip;
    return __builtin_bit_cast(short8v, r);
}

__device__ __forceinline__ void mkpat(unsigned pat[4], int l15) {
    const int jl = l15 & 7;
    #pragma unroll
    for (int d = 0; d < 4; ++d) {
        unsigned lo = (__popc((2 * d) & jl) & 1) ? 0xBF80u : 0x3F80u;
        unsigned hi = (__popc((2 * d + 1) & jl) & 1) ? 0xBF80u : 0x3F80u;
        pat[d] = lo | (hi << 16);
    }
}

// ---------------- K1: forward FWHT via Kronecker (H * X * H), MFMA ------------
// Row (b,i) reshaped X[a][c] (n = a*64+c). GEMM1: tmp = X*H (over c);
// GEMM2: f1 = H*tmp (over a). Output written in k_mix's tiled layout
// f1t[b][chunk][i][nl], chunk = n'>>5, nl = n'&31.
__global__ __launch_bounds__(256) void k_fwht_fwd(const float* __restrict__ x,
                                                  unsigned short* __restrict__ f1t,
                                                  const float* __restrict__ W,
                                                  unsigned short* __restrict__ Wb) {
    __shared__ unsigned short sX[64 * HST];   // X[a][c] bf16
    __shared__ unsigned short sT[64 * HST];   // tmp[c'][a] bf16 (B-read layout)
    const int row = blockIdx.x;            // b*64 + i
    const int t = threadIdx.x;
    const int b = row >> 6, i = row & 63;
    const int lane = t & 63, w = t >> 6;
    const int l15 = lane & 15, lq = lane >> 4;

    if (row < NP * CH && t < CH)           // W -> bf16 copy (once)
        Wb[row * CH + t] = f2bu(W[row * CH + t]);

    {   // stage X: thread t -> 16 elems at n = t*16 (t<250 real, else pad)
        unsigned short e16[16];
        if (t < 250) {
            const float* xr = x + (size_t)row * LENGTH + t * 16;
            #pragma unroll
            for (int q = 0; q < 4; ++q) {
                float4 lv = *(const float4*)(xr + q * 4);
                e16[q * 4 + 0] = f2bu(lv.x); e16[q * 4 + 1] = f2bu(lv.y);
                e16[q * 4 + 2] = f2bu(lv.z); e16[q * 4 + 3] = f2bu(lv.w);
            }
        } else {
            #pragma unroll
            for (int q = 0; q < 16; ++q) e16[q] = 0;
        }
        const int a = t >> 2, c0 = (t & 3) * 16;
        *(ushort8*)&sX[a * HST + c0]     = *(ushort8*)&e16[0];
        *(ushort8*)&sX[a * HST + c0 + 8] = *(ushort8*)&e16[8];
    }

    unsigned pat[4];
    mkpat(pat, l15);
    __syncthreads();

    // GEMM1: tmp[a][c'] = sum_c X[a][c] H[c][c'];  wave w owns a-rows w*16..+15
    f32x4 acc[4];
    #pragma unroll
    for (int nt = 0; nt < 4; ++nt) acc[nt] = (f32x4){0.f, 0.f, 0.f, 0.f};
    #pragma unroll
    for (int ks = 0; ks < 2; ++ks) {
        const int k0 = ks * 32 + lq * 8;
        short8v af = *(const short8v*)&sX[(w * 16 + l15) * HST + k0];
        #pragma unroll
        for (int nt = 0; nt < 4; ++nt)
            acc[nt] = __builtin_amdgcn_mfma_f32_16x16x32_bf16(
                af, hfrag(pat, nt * 16 + l15, k0), acc[nt], 0, 0, 0);
    }
    // write tmp -> sT[c'][a]: C tile col=c'=nt*16+l15, rows a=w*16+lq*4+r
    #pragma unroll
    for (int nt = 0; nt < 4; ++nt) {
        ushort4v u;
        u[0] = f2bu(acc[nt][0]); u[1] = f2bu(acc[nt][1]);
        u[2] = f2bu(acc[nt][2]); u[3] = f2bu(acc[nt][3]);
        *(ushort4v*)&sT[(nt * 16 + l15) * HST + w * 16 + lq * 4] = u;
    }
    __syncthreads();

    // GEMM2: f1[a'][c'] = sum_a H[a][a'] tmp[a][c'];  A = H (sym), B from sT
    f32x4 acc2[4];
    #pragma unroll
    for (int nt = 0; nt < 4; ++nt) acc2[nt] = (f32x4){0.f, 0.f, 0.f, 0.f};
    #pragma unroll
    for (int ks = 0; ks < 2; ++ks) {
        const int k0 = ks * 32 + lq * 8;
        short8v af = hfrag(pat, w * 16 + l15, k0);
        #pragma unroll
        for (int nt = 0; nt < 4; ++nt) {
            short8v bf = *(const short8v*)&sT[(nt * 16 + l15) * HST + k0];
            acc2[nt] = __builtin_amdgcn_mfma_f32_16x16x32_bf16(
                af, bf, acc2[nt], 0, 0, 0);
        }
    }
    // store tiled: n' = a'*64 + c'; chunk = a'*2 + (nt>>1), nl = (nt&1)*16+l15
    #pragma unroll
    for (int nt = 0; nt < 4; ++nt) {
        const int nl = (nt & 1) * 16 + l15;
        #pragma unroll
        for (int r = 0; r < 4; ++r) {
            const int ap = w * 16 + lq * 4 + r;
            f1t[((size_t)(b * 128 + ap * 2 + (nt >> 1)) * 64 + i) * 32 + nl] =
                f2bu(acc2[nt][r]);
        }
    }
}

// ---------------- K2: MFMA channel mix (R15, unchanged) -----------------------
__global__ __launch_bounds__(256) void k_mix(const unsigned short* __restrict__ f1t,
                                             const unsigned short* __restrict__ Wb,
                                             const float* __restrict__ T,
                                             const float* __restrict__ v,
                                             unsigned short* __restrict__ f6b) {
    __shared__ unsigned short sBt[NT2 * BSTR];   // [n][i] transposed, 4.6 KB
    const int bid = blockIdx.x;            // b*128 + nchunk
    const int nchunk = bid & 127;
    const int b = bid >> 7;
    const int nbase = nchunk * NT2;
    const int t = threadIdx.x;
    const int lane = t & 63;
    const int w = t >> 6;                  // wave id 0..3
    const int l15 = lane & 15, lq = lane >> 4;

    {   // stage tile: ONE contiguous 4KB block (tiled [i][nl] layout)
        const unsigned short* src =
            f1t + (size_t)(b * 128 + nchunk) * (64 * 32) + t * 8;
        ushort8 r = *(const ushort8*)src;
        const int i = t >> 2, n0 = (t & 3) * 8;
        #pragma unroll
        for (int j = 0; j < 8; ++j)
            sBt[(n0 + j) * BSTR + i] = r[j];
    }

    short8v afrag[NP][2];
    #pragma unroll
    for (int p = 0; p < NP; ++p)
        #pragma unroll
        for (int ks = 0; ks < 2; ++ks)
            afrag[p][ks] = *(const short8v*)(Wb +
                (size_t)(p * 64 + w * 16 + l15) * CH + ks * 32 + lq * 8);

    float vp_[2][NP], tp_[2][NP];
    #pragma unroll
    for (int nt = 0; nt < 2; ++nt) {
        const int n = nbase + nt * 16 + l15;
        #pragma unroll
        for (int p = 0; p < NP; ++p) {
            vp_[nt][p] = v[(size_t)p * NPAD + n];
            tp_[nt][p] = fabsf(T[(size_t)p * NPAD + n]);
        }
    }

    __syncthreads();

    short8v bfrag[2][2];
    #pragma unroll
    for (int nt = 0; nt < 2; ++nt)
        #pragma unroll
        for (int ks = 0; ks < 2; ++ks)
            bfrag[nt][ks] = *(const short8v*)(
                &sBt[(nt * 16 + l15) * BSTR + ks * 32 + lq * 8]);

    f32x4 acc[NP][2];
    #pragma unroll
    for (int p = 0; p < NP; ++p)
        #pragma unroll
        for (int nt = 0; nt < 2; ++nt) {
            acc[p][nt] = (f32x4){0.f, 0.f, 0.f, 0.f};
            #pragma unroll
            for (int ks = 0; ks < 2; ++ks)
                acc[p][nt] = __builtin_amdgcn_mfma_f32_16x16x32_bf16(
                    afrag[p][ks], bfrag[nt][ks], acc[p][nt], 0, 0, 0);
        }

    #pragma unroll
    for (int nt = 0; nt < 2; ++nt) {
        const int n = nbase + nt * 16 + l15;
        float outv[4] = {0.f, 0.f, 0.f, 0.f};
        #pragma unroll
        for (int p = 0; p < NP; ++p) {
            #pragma unroll
            for (int r = 0; r < 4; ++r) {
                float c = vp_[nt][p] * acc[p][nt][r];
                float a = fabsf(c) - tp_[nt][p];
                outv[r] += (a > 0.f) ? copysignf(a, c) : 0.f;
            }
        }
        #pragma unroll
        for (int r = 0; r < 4; ++r) {
            const int o = w * 16 + lq * 4 + r;
            f6b[(size_t)(b * CH + o) * NPAD + n] = f2bu(outv[r]);
        }
    }
}

// ---------------- K3: inverse FWHT via Kronecker, scale, trunc, +x ------------
// Row (b,o): F6[a'][c'] -> GEMM1: U2 = F6*H (over c') -> GEMM2: Y = H*U2
// (over a') -> y[n]*1/4096 + x[n], n = a*64+c < 4000.
__global__ __launch_bounds__(256) void k_fwht_inv(const unsigned short* __restrict__ f6b,
                                                  const float* __restrict__ x,
                                                  float* __restrict__ out) {
    __shared__ unsigned short sM[64 * HST];   // F6[a'][c']
    __shared__ unsigned short sT[64 * HST];   // U2[c][a'] (B-read layout)
    const int row = blockIdx.x;            // b*64 + o
    const int t = threadIdx.x;
    const int lane = t & 63, w = t >> 6;
    const int l15 = lane & 15, lq = lane >> 4;

    {   // stage f6 row: contiguous 8KB read
        const unsigned short* fr = f6b + (size_t)row * NPAD + t * 16;
        ushort8 r0 = *(const ushort8*)fr;
        ushort8 r1 = *(const ushort8*)(fr + 8);
        const int ap = t >> 2, c0 = (t & 3) * 16;
        *(ushort8*)&sM[ap * HST + c0]     = r0;
        *(ushort8*)&sM[ap * HST + c0 + 8] = r1;
    }

    unsigned pat[4];
    mkpat(pat, l15);
    __syncthreads();

    // GEMM1: U2[a'][c] = sum_{c'} F6[a'][c'] H[c'][c]
    f32x4 acc[4];
    #pragma unroll
    for (int nt = 0; nt < 4; ++nt) acc[nt] = (f32x4){0.f, 0.f, 0.f, 0.f};
    #pragma unroll
    for (int ks = 0; ks < 2; ++ks) {
        const int k0 = ks * 32 + lq * 8;
        short8v af = *(const short8v*)&sM[(w * 16 + l15) * HST + k0];
        #pragma unroll
        for (int nt = 0; nt < 4; ++nt)
            acc[nt] = __builtin_amdgcn_mfma_f32_16x16x32_bf16(
                af, hfrag(pat, nt * 16 + l15, k0), acc[nt], 0, 0, 0);
    }
    #pragma unroll
    for (int nt = 0; nt < 4; ++nt) {      // U2 -> sT[c][a']
        ushort4v u;
        u[0] = f2bu(acc[nt][0]); u[1] = f2bu(acc[nt][1]);
        u[2] = f2bu(acc[nt][2]); u[3] = f2bu(acc[nt][3]);
        *(ushort4v*)&sT[(nt * 16 + l15) * HST + w * 16 + lq * 4] = u;
    }
    __syncthreads();

    // GEMM2: Y[a][c] = sum_{a'} H[a'][a] U2[a'][c]
    f32x4 acc2[4];
    #pragma unroll
    for (int nt = 0; nt < 4; ++nt) acc2[nt] = (f32x4){0.f, 0.f, 0.f, 0.f};
    #pragma unroll
    for (int ks = 0; ks < 2; ++ks) {
        const int k0 = ks * 32 + lq * 8;
        short8v af = hfrag(pat, w * 16 + l15, k0);
        #pragma unroll
        for (int nt = 0; nt < 4; ++nt) {
            short8v bf = *(const short8v*)&sT[(nt * 16 + l15) * HST + k0];
            acc2[nt] = __builtin_amdgcn_mfma_f32_16x16x32_bf16(
                af, bf, acc2[nt], 0, 0, 0);
        }
    }

    const float scale = 1.f / NPAD;
    const float* xr = x + (size_t)row * LENGTH;
    float* orow = out + (size_t)row * LENGTH;
    #pragma unroll
    for (int nt = 0; nt < 4; ++nt) {
        const int c = nt * 16 + l15;
        #pragma unroll
        for (int r = 0; r < 4; ++r) {
            const int a = w * 16 + lq * 4 + r;
            const int n = a * 64 + c;
            if (n < LENGTH) orow[n] = acc2[nt][r] * scale + xr[n];
        }
    }
}

extern "C" void kernel_launch(void* const* d_in, const int* in_sizes, int n_in,
                              void* d_out, int out_size, void* d_ws, size_t ws_size,
                              hipStream_t stream) {
    (void)in_sizes; (void)n_in; (void)out_size; (void)ws_size;
    const float* x = (const float*)d_in[0];
    const float* W = (const float*)d_in[1];
    const float* T = (const float*)d_in[2];
    const float* v = (const float*)d_in[3];
    float* out = (float*)d_out;
    unsigned short* f1t = (unsigned short*)d_ws;                 // 4 MB (tiled)
    unsigned short* f6b = f1t + (size_t)NB * CH * NPAD;          // 4 MB
    unsigned short* Wb  = f6b + (size_t)NB * CH * NPAD;          // 32 KB

    k_fwht_fwd<<<NB * CH, 256, 0, stream>>>(x, f1t, W, Wb);
    k_mix<<<NB * (NPAD / NT2), 256, 0, stream>>>(f1t, Wb, T, v, f6b);
    k_fwht_inv<<<NB * CH, 256, 0, stream>>>(f6b, x, out);
}

// Round 17
// 22.879 us; speedup vs baseline: 1.0278x; 1.0278x over previous
//
#include <hip/hip_runtime.h>
#include <hip/hip_bf16.h>

#define LENGTH 4000
#define NPAD   4096
#define NB     8
#define CH     64
#define NP     4
#define NT2    32               // n-cols per k_mix block
#define BSTR   72               // sBt row stride (ushorts) = 9*16B: aligned b128 rows

using ushort8 = __attribute__((ext_vector_type(8))) unsigned short;
using short8v = __attribute__((ext_vector_type(8))) short;
using f32x4   = __attribute__((ext_vector_type(4))) float;

__device__ __forceinline__ unsigned short f2bu(float f) {
    __hip_bfloat16 h = __float2bfloat16(f);
    return __builtin_bit_cast(unsigned short, h);
}
__device__ __forceinline__ float bu2f(unsigned short u) {
    __hip_bfloat16 h = __builtin_bit_cast(__hip_bfloat16, u);
    return __bfloat162float(h);
}

// 8-point unnormalized Sylvester FWHT in registers.
__device__ __forceinline__ void fwht8(float v[8]) {
    #pragma unroll
    for (int h = 1; h < 8; h <<= 1)
        #pragma unroll
        for (int j = 0; j < 8; j += 2 * h)
            #pragma unroll
            for (int k = j; k < j + h; ++k) {
                float a = v[k], b = v[k + h];
                v[k] = a + b; v[k + h] = a - b;
            }
}

// Padded LDS address: every 8-float group padded by 1 -> all digit-stride
// exchanges are <=3-way bank aliased.
#define LADR(n) ((((n) >> 3) * 9) + ((n) & 7))
#define LDSZ 4608   // 4096/8*9

// f1 is stored CHUNK-TILED for k_mix: f1t[b][chunk(128)][i(64)][nl(32)].
// k_mix (sole consumer) then stages one contiguous 4KB block instead of 64
// stride-4096 segments.

// ---------------- K1: forward FWHT (radix 8^4, 512 thr) -> f1t bf16 -----------
__global__ __launch_bounds__(512) void k_fwht_fwd(const float* __restrict__ x,
                                                  unsigned short* __restrict__ f1t,
                                                  const float* __restrict__ W,
                                                  unsigned short* __restrict__ Wb) {
    __shared__ float ldsA[LDSZ];
    __shared__ float ldsB[LDSZ];
    const int row = blockIdx.x;            // b*64 + i
    const int t = threadIdx.x;

    if (row < NP * CH && t < CH)           // W[po][i] -> bf16 copy (once)
        Wb[row * CH + t] = f2bu(W[row * CH + t]);

    float v[8];
    if (t < 500) {                         // 500*8 == 4000
        const float* xr = x + (size_t)row * LENGTH + t * 8;
        float4 a = *(const float4*)xr, b = *(const float4*)(xr + 4);
        v[0]=a.x; v[1]=a.y; v[2]=a.z; v[3]=a.w;
        v[4]=b.x; v[5]=b.y; v[6]=b.z; v[7]=b.w;
    } else {
        #pragma unroll
        for (int j = 0; j < 8; ++j) v[j] = 0.f;
    }
    fwht8(v);                              // over d0

    #pragma unroll
    for (int j = 0; j < 8; ++j) ldsA[LADR(t * 8 + j)] = v[j];
    __syncthreads();
    const int s1 = (t >> 3) * 64 + (t & 7);
    #pragma unroll
    for (int j = 0; j < 8; ++j) v[j] = ldsA[LADR(s1 + j * 8)];
    fwht8(v);                              // over d1

    #pragma unroll
    for (int j = 0; j < 8; ++j) ldsB[LADR(s1 + j * 8)] = v[j];
    __syncthreads();
    const int s2 = (t >> 6) * 512 + ((t >> 3) & 7) * 8 + (t & 7);
    #pragma unroll
    for (int j = 0; j < 8; ++j) v[j] = ldsB[LADR(s2 + j * 64)];
    fwht8(v);                              // over d2

    #pragma unroll
    for (int j = 0; j < 8; ++j) ldsA[LADR(s2 + j * 64)] = v[j];
    __syncthreads();
    #pragma unroll
    for (int j = 0; j < 8; ++j) v[j] = ldsA[LADR(j * 512 + t)];
    fwht8(v);                              // over d3

    // tiled store: n = j*512+t -> [b][n>>5][i][n&31]
    const int b = row >> 6, i = row & 63;
    unsigned short* fb = f1t + ((size_t)b * 128 * 64 + (size_t)i) * 32;
    #pragma unroll
    for (int j = 0; j < 8; ++j) {
        const int n = j * 512 + t;
        fb[(size_t)(n >> 5) * (64 * 32) + (n & 31)] = f2bu(v[j]);
    }
}

// ---------------- K2: MFMA channel mix (tiled staging + hoisted v/T) ----------
__global__ __launch_bounds__(256) void k_mix(const unsigned short* __restrict__ f1t,
                                             const unsigned short* __restrict__ Wb,
                                             const float* __restrict__ T,
                                             const float* __restrict__ v,
                                             unsigned short* __restrict__ f6b) {
    __shared__ unsigned short sBt[NT2 * BSTR];   // [n][i] transposed, 4.6 KB
    const int bid = blockIdx.x;            // b*128 + nchunk
    const int nchunk = bid & 127;
    const int b = bid >> 7;
    const int nbase = nchunk * NT2;
    const int t = threadIdx.x;
    const int lane = t & 63;
    const int w = t >> 6;                  // wave id 0..3
    const int l15 = lane & 15, lq = lane >> 4;

    {   // stage tile: ONE contiguous 4KB block (tiled [i][nl] layout)
        const unsigned short* src =
            f1t + (size_t)(b * 128 + nchunk) * (64 * 32) + t * 8;
        ushort8 r = *(const ushort8*)src;
        const int i = t >> 2, n0 = (t & 3) * 8;
        #pragma unroll
        for (int j = 0; j < 8; ++j)
            sBt[(n0 + j) * BSTR + i] = r[j];
    }

    short8v afrag[NP][2];
    #pragma unroll
    for (int p = 0; p < NP; ++p)
        #pragma unroll
        for (int ks = 0; ks < 2; ++ks)
            afrag[p][ks] = *(const short8v*)(Wb +
                (size_t)(p * 64 + w * 16 + l15) * CH + ks * 32 + lq * 8);

    // hoist v/T loads: latency hides under barrier + MFMA phase
    float vp_[2][NP], tp_[2][NP];
    #pragma unroll
    for (int nt = 0; nt < 2; ++nt) {
        const int n = nbase + nt * 16 + l15;
        #pragma unroll
        for (int p = 0; p < NP; ++p) {
            vp_[nt][p] = v[(size_t)p * NPAD + n];
            tp_[nt][p] = fabsf(T[(size_t)p * NPAD + n]);
        }
    }

    __syncthreads();

    short8v bfrag[2][2];
    #pragma unroll
    for (int nt = 0; nt < 2; ++nt)
        #pragma unroll
        for (int ks = 0; ks < 2; ++ks)
            bfrag[nt][ks] = *(const short8v*)(
                &sBt[(nt * 16 + l15) * BSTR + ks * 32 + lq * 8]);

    f32x4 acc[NP][2];
    #pragma unroll
    for (int p = 0; p < NP; ++p)
        #pragma unroll
        for (int nt = 0; nt < 2; ++nt) {
            acc[p][nt] = (f32x4){0.f, 0.f, 0.f, 0.f};
            #pragma unroll
            for (int ks = 0; ks < 2; ++ks)
                acc[p][nt] = __builtin_amdgcn_mfma_f32_16x16x32_bf16(
                    afrag[p][ks], bfrag[nt][ks], acc[p][nt], 0, 0, 0);
        }

    // epilogue: v*, soft-threshold, sum over p; C layout col=lane&15,
    // row=(lane>>4)*4+reg  [learn_hip m89]
    #pragma unroll
    for (int nt = 0; nt < 2; ++nt) {
        const int n = nbase + nt * 16 + l15;
        float outv[4] = {0.f, 0.f, 0.f, 0.f};
        #pragma unroll
        for (int p = 0; p < NP; ++p) {
            #pragma unroll
            for (int r = 0; r < 4; ++r) {
                float c = vp_[nt][p] * acc[p][nt][r];
                float a = fabsf(c) - tp_[nt][p];
                outv[r] += (a > 0.f) ? copysignf(a, c) : 0.f;
            }
        }
        #pragma unroll
        for (int r = 0; r < 4; ++r) {
            const int o = w * 16 + lq * 4 + r;
            f6b[(size_t)(b * CH + o) * NPAD + n] = f2bu(outv[r]);
        }
    }
}

// ---------------- K3: inverse FWHT (radix 8^4), scale, trunc, +x --------------
__global__ __launch_bounds__(512) void k_fwht_inv(const unsigned short* __restrict__ f6b,
                                                  const float* __restrict__ x,
                                                  float* __restrict__ out) {
    __shared__ float ldsA[LDSZ];
    __shared__ float ldsB[LDSZ];
    const int row = blockIdx.x;            // b*64 + o
    const int t = threadIdx.x;

    float v[8];
    {
        const unsigned short* fr = f6b + (size_t)row * NPAD + t * 8;
        ushort8 r = *(const ushort8*)fr;
        #pragma unroll
        for (int j = 0; j < 8; ++j) v[j] = bu2f(r[j]);
    }
    fwht8(v);                              // d0

    #pragma unroll
    for (int j = 0; j < 8; ++j) ldsA[LADR(t * 8 + j)] = v[j];
    __syncthreads();
    const int s1 = (t >> 3) * 64 + (t & 7);
    #pragma unroll
    for (int j = 0; j < 8; ++j) v[j] = ldsA[LADR(s1 + j * 8)];
    fwht8(v);                              // d1

    #pragma unroll
    for (int j = 0; j < 8; ++j) ldsB[LADR(s1 + j * 8)] = v[j];
    __syncthreads();
    const int s2 = (t >> 6) * 512 + ((t >> 3) & 7) * 8 + (t & 7);
    #pragma unroll
    for (int j = 0; j < 8; ++j) v[j] = ldsB[LADR(s2 + j * 64)];
    fwht8(v);                              // d2

    #pragma unroll
    for (int j = 0; j < 8; ++j) ldsA[LADR(s2 + j * 64)] = v[j];
    __syncthreads();
    #pragma unroll
    for (int j = 0; j < 8; ++j) v[j] = ldsA[LADR(j * 512 + t)];
    fwht8(v);                              // d3

    const float scale = 1.f / NPAD;
    const float* xr = x + (size_t)row * LENGTH;
    float* orow = out + (size_t)row * LENGTH;
    #pragma unroll
    for (int j = 0; j < 8; ++j) {
        const int n = j * 512 + t;
        if (n < LENGTH) orow[n] = v[j] * scale + xr[n];
    }
}

extern "C" void kernel_launch(void* const* d_in, const int* in_sizes, int n_in,
                              void* d_out, int out_size, void* d_ws, size_t ws_size,
                              hipStream_t stream) {
    (void)in_sizes; (void)n_in; (void)out_size; (void)ws_size;
    const float* x = (const float*)d_in[0];
    const float* W = (const float*)d_in[1];
    const float* T = (const float*)d_in[2];
    const float* v = (const float*)d_in[3];
    float* out = (float*)d_out;
    unsigned short* f1t = (unsigned short*)d_ws;                 // 4 MB (tiled)
    unsigned short* f6b = f1t + (size_t)NB * CH * NPAD;          // 4 MB
    unsigned short* Wb  = f6b + (size_t)NB * CH * NPAD;          // 32 KB

    k_fwht_fwd<<<NB * CH, 512, 0, stream>>>(x, f1t, W, Wb);
    k_mix<<<NB * (NPAD / NT2), 256, 0, stream>>>(f1t, Wb, T, v, f6b);
    k_fwht_inv<<<NB * CH, 512, 0, stream>>>(f6b, x, out);
}